// Round 5
// baseline (610.629 us; speedup 1.0000x reference)
//
#include <hip/hip_runtime.h>

typedef __attribute__((ext_vector_type(8))) short short8;
typedef __attribute__((ext_vector_type(4))) float float4v;

#define N_PTS 8192
#define DIM   128
#define BM    128

typedef const __attribute__((address_space(1))) void* gptr_t;
typedef __attribute__((address_space(3))) void* lptr_t;

__device__ __forceinline__ unsigned short f2bf(float f) {
    unsigned u = __builtin_bit_cast(unsigned, f);
    u += 0x7fffu + ((u >> 16) & 1u);          // RNE to bf16
    return (unsigned short)(u >> 16);
}
__device__ __forceinline__ float bf2f(unsigned short h) {
    unsigned u = ((unsigned)h) << 16;
    return __builtin_bit_cast(float, u);
}

// DIAGNOSTIC ROUND: tail-spin (100 MHz s_memrealtime ticks) pushes each kernel
// past the ~170 us poison fills so its true FETCH_SIZE/WRITE_SIZE/conflict
// counters surface in the top-5 table. No memory traffic from the spin.
__device__ __forceinline__ void tail_spin(long long ticks) {
    long long t0 = (long long)__builtin_amdgcn_s_memrealtime();
    while ((long long)__builtin_amdgcn_s_memrealtime() - t0 < ticks)
        __builtin_amdgcn_s_sleep(8);
}

// ---- pre-pass: fp32 -> bf16 once, XOR-swizzled granules, plus per-row sq ----
// (verbatim from the verified 271 us kernel, + 180 us tail spin:
//  prep_true = dispatch_dur - 180 us, single generation of 64 blocks)
__global__ __launch_bounds__(128)
void prep_kernel(const float* __restrict__ F,
                 unsigned short* __restrict__ bfF,
                 float* __restrict__ sqg) {
    const int row = blockIdx.x * 128 + threadIdx.x;   // 64 blocks x 128 = 8192 rows
    const float* __restrict__ src = F + (size_t)row * DIM;
    unsigned short* dst = bfF + (size_t)row * DIM;
    float s = 0.f;
#pragma unroll
    for (int g = 0; g < 16; ++g) {
        float4v f0 = *(const float4v*)(src + g * 8);
        float4v f1 = *(const float4v*)(src + g * 8 + 4);
        short8 p;
#pragma unroll
        for (int k = 0; k < 4; ++k) {
            unsigned short b0 = f2bf(f0[k]);
            unsigned short b1 = f2bf(f1[k]);
            p[k]     = (short)b0;
            p[k + 4] = (short)b1;
            float v0 = bf2f(b0), v1 = bf2f(b1);
            s += v0 * v0 + v1 * v1;
        }
        *(short8*)(dst + (g ^ (row & 15)) * 8) = p;
    }
    sqg[row] = s;
    tail_spin(18000);   // +180 us
}

// ---- main: verbatim round-0 (271 us) kernel + 20 us per-block tail spin ----
// With S resident blocks: dur ~= (4096/S)*20us + fsim_true.
//   S=512 (2/CU): fsim_true ~= dur - 160 us.  S=256 would push dur past 400.
__global__ __launch_bounds__(256, 2)
void fsim_kernel(const unsigned short* __restrict__ bfF,
                 const float* __restrict__ sqg,
                 float* __restrict__ out) {
    __shared__ unsigned short As[BM * DIM];   // 32 KB (swizzled bf16)
    __shared__ unsigned short Bs[BM * DIM];   // 32 KB
    __shared__ float sqA[BM];
    __shared__ float sqB[BM];

    const int t    = threadIdx.x;
    const int lane = t & 63;
    const int w    = t >> 6;
    const int brow = blockIdx.y;
    const int bcol = blockIdx.x;

    // ---- stage: linear global->LDS DMA, 16 B/lane, zero VALU conversion ----
    const char* gA = (const char*)(bfF + (size_t)brow * BM * DIM);
    const char* gB = (const char*)(bfF + (size_t)bcol * BM * DIM);
    char* lA = (char*)As;
    char* lB = (char*)Bs;
    const int off = w * 8192 + lane * 16;     // each wave copies 8 KB per tile
#pragma unroll
    for (int i = 0; i < 8; ++i) {
        __builtin_amdgcn_global_load_lds((gptr_t)(gA + off + i * 1024),
                                         (lptr_t)(lA + off + i * 1024), 16, 0, 0);
        __builtin_amdgcn_global_load_lds((gptr_t)(gB + off + i * 1024),
                                         (lptr_t)(lB + off + i * 1024), 16, 0, 0);
    }
    // sq rows for this tile (L2-hot, 1 KB total)
    if (t < 128) sqA[t] = sqg[brow * BM + t];
    else         sqB[t - 128] = sqg[bcol * BM + (t - 128)];
    __syncthreads();                          // compiler drains vmcnt here

    // ---- MFMA k-loop: gram = Fb * Fb^T, K=128 in 4 steps ----
    const int wr   = (w >> 1) * 64;
    const int wc   = (w & 1) * 64;
    const int lrow = lane & 15;
    const int quad = lane >> 4;

    float4v acc[4][4];
#pragma unroll
    for (int a = 0; a < 4; ++a)
#pragma unroll
        for (int b = 0; b < 4; ++b)
            acc[a][b] = (float4v){0.f, 0.f, 0.f, 0.f};

#pragma unroll
    for (int ks = 0; ks < 4; ++ks) {
        short8 af[4], bfv[4];
        const int g = ks * 4 + quad;          // logical granule along K
#pragma unroll
        for (int mt = 0; mt < 4; ++mt) {
            const int row = wr + mt * 16 + lrow;
            af[mt] = *(const short8*)((const short*)As + row * DIM + ((g ^ (row & 15)) * 8));
        }
#pragma unroll
        for (int nt = 0; nt < 4; ++nt) {
            const int row = wc + nt * 16 + lrow;
            bfv[nt] = *(const short8*)((const short*)Bs + row * DIM + ((g ^ (row & 15)) * 8));
        }
#pragma unroll
        for (int mt = 0; mt < 4; ++mt)
#pragma unroll
            for (int nt = 0; nt < 4; ++nt)
                acc[mt][nt] = __builtin_amdgcn_mfma_f32_16x16x32_bf16(
                    af[mt], bfv[nt], acc[mt][nt], 0, 0, 0);
    }

    // ---- epilogue: -sqrt(max(0, sq_r + sq_c - 2*gram)) ----
    const size_t orow0    = (size_t)brow * BM;
    const int    col_base = bcol * BM;
    float scb[4];
#pragma unroll
    for (int nt = 0; nt < 4; ++nt) scb[nt] = sqB[wc + nt * 16 + lrow];
#pragma unroll
    for (int mt = 0; mt < 4; ++mt) {
#pragma unroll
        for (int reg = 0; reg < 4; ++reg) {
            const int m  = wr + mt * 16 + quad * 4 + reg;  // C/D: row=(lane>>4)*4+reg, col=lane&15
            const float sr = sqA[m];
            float* orow = out + (orow0 + m) * (size_t)N_PTS + col_base;
#pragma unroll
            for (int nt = 0; nt < 4; ++nt) {
                const int n = wc + nt * 16 + lrow;
                float d2 = sr + scb[nt] - 2.0f * acc[mt][nt][reg];
                d2 = d2 > 0.f ? d2 : 0.f;
                orow[n] = -__builtin_sqrtf(d2);
            }
        }
    }
    tail_spin(2000);    // +20 us per block residency
}

extern "C" void kernel_launch(void* const* d_in, const int* in_sizes, int n_in,
                              void* d_out, int out_size, void* d_ws, size_t ws_size,
                              hipStream_t stream) {
    const float* F = (const float*)d_in[0];
    float* out = (float*)d_out;
    unsigned short* bfF = (unsigned short*)d_ws;                       // 2 MB bf16
    float* sqg = (float*)((char*)d_ws + (size_t)N_PTS * DIM * 2);      // +32 KB sq

    prep_kernel<<<dim3(N_PTS / 128), 128, 0, stream>>>(F, bfF, sqg);
    dim3 grid(N_PTS / BM, N_PTS / BM);        // 64 x 64
    fsim_kernel<<<grid, 256, 0, stream>>>(bfF, sqg, out);
}

// Round 6
// 271.761 us; speedup vs baseline: 2.2469x; 2.2469x over previous
//
#include <hip/hip_runtime.h>

typedef __attribute__((ext_vector_type(8))) short short8;
typedef __attribute__((ext_vector_type(4))) float float4v;

#define N_PTS 8192
#define DIM   128
#define BM    128

typedef const __attribute__((address_space(1))) void* gptr_t;
typedef __attribute__((address_space(3))) void* lptr_t;

__device__ __forceinline__ unsigned short f2bf(float f) {
    unsigned u = __builtin_bit_cast(unsigned, f);
    u += 0x7fffu + ((u >> 16) & 1u);          // RNE to bf16
    return (unsigned short)(u >> 16);
}
__device__ __forceinline__ float bf2f(unsigned short h) {
    unsigned u = ((unsigned)h) << 16;
    return __builtin_bit_cast(float, u);
}

// ---- pre-pass: fp32 -> bf16, XOR-swizzled granules, per-row sq ----
// REWRITTEN (the one change this round): 16 threads/row, 512 blocks x 256
// threads = 2048 waves on 256 CUs (was 64 blocks / 128 waves, ~40 us
// latency-bound). Each thread: one 32 B coalesced granule load, RNE convert,
// one 16 B swizzled store (16-lane group covers a contiguous 256 B row),
// 4-step shfl_xor tree for sq. Swizzle contract unchanged:
// logical granule g of row r lands at slot g ^ (r & 15).
__global__ __launch_bounds__(256)
void prep_kernel(const float* __restrict__ F,
                 unsigned short* __restrict__ bfF,
                 float* __restrict__ sqg) {
    const int tid  = blockIdx.x * 256 + threadIdx.x;   // 131072 = 8192 rows x 16
    const int row  = tid >> 4;
    const int part = tid & 15;                          // logical granule index
    const float* __restrict__ src = F + (size_t)row * DIM + part * 8;
    float4v f0 = *(const float4v*)(src);
    float4v f1 = *(const float4v*)(src + 4);
    short8 p;
    float s = 0.f;
#pragma unroll
    for (int k = 0; k < 4; ++k) {
        unsigned short b0 = f2bf(f0[k]);
        unsigned short b1 = f2bf(f1[k]);
        p[k]     = (short)b0;
        p[k + 4] = (short)b1;
        float v0 = bf2f(b0), v1 = bf2f(b1);
        s += v0 * v0 + v1 * v1;
    }
    *(short8*)(bfF + (size_t)row * DIM + ((part ^ (row & 15)) * 8)) = p;
    // sq: reduce over the 16-lane group (lanes of one row)
    s += __shfl_xor(s, 1);
    s += __shfl_xor(s, 2);
    s += __shfl_xor(s, 4);
    s += __shfl_xor(s, 8);
    if (part == 0) sqg[row] = s;
}

// ---- main: 128x128 output tile per block, bf16 MFMA, DMA staging ----
// VERBATIM round-0 verified kernel (271 us, absmax 0.125). No changes.
__global__ __launch_bounds__(256, 2)
void fsim_kernel(const unsigned short* __restrict__ bfF,
                 const float* __restrict__ sqg,
                 float* __restrict__ out) {
    __shared__ unsigned short As[BM * DIM];   // 32 KB (swizzled bf16)
    __shared__ unsigned short Bs[BM * DIM];   // 32 KB
    __shared__ float sqA[BM];
    __shared__ float sqB[BM];

    const int t    = threadIdx.x;
    const int lane = t & 63;
    const int w    = t >> 6;
    const int brow = blockIdx.y;
    const int bcol = blockIdx.x;

    // ---- stage: linear global->LDS DMA, 16 B/lane, zero VALU conversion ----
    const char* gA = (const char*)(bfF + (size_t)brow * BM * DIM);
    const char* gB = (const char*)(bfF + (size_t)bcol * BM * DIM);
    char* lA = (char*)As;
    char* lB = (char*)Bs;
    const int off = w * 8192 + lane * 16;     // each wave copies 8 KB per tile
#pragma unroll
    for (int i = 0; i < 8; ++i) {
        __builtin_amdgcn_global_load_lds((gptr_t)(gA + off + i * 1024),
                                         (lptr_t)(lA + off + i * 1024), 16, 0, 0);
        __builtin_amdgcn_global_load_lds((gptr_t)(gB + off + i * 1024),
                                         (lptr_t)(lB + off + i * 1024), 16, 0, 0);
    }
    // sq rows for this tile (L2-hot, 1 KB total)
    if (t < 128) sqA[t] = sqg[brow * BM + t];
    else         sqB[t - 128] = sqg[bcol * BM + (t - 128)];
    __syncthreads();                          // compiler drains vmcnt here

    // ---- MFMA k-loop: gram = Fb * Fb^T, K=128 in 4 steps ----
    const int wr   = (w >> 1) * 64;
    const int wc   = (w & 1) * 64;
    const int lrow = lane & 15;
    const int quad = lane >> 4;

    float4v acc[4][4];
#pragma unroll
    for (int a = 0; a < 4; ++a)
#pragma unroll
        for (int b = 0; b < 4; ++b)
            acc[a][b] = (float4v){0.f, 0.f, 0.f, 0.f};

#pragma unroll
    for (int ks = 0; ks < 4; ++ks) {
        short8 af[4], bfv[4];
        const int g = ks * 4 + quad;          // logical granule along K
#pragma unroll
        for (int mt = 0; mt < 4; ++mt) {
            const int row = wr + mt * 16 + lrow;
            af[mt] = *(const short8*)((const short*)As + row * DIM + ((g ^ (row & 15)) * 8));
        }
#pragma unroll
        for (int nt = 0; nt < 4; ++nt) {
            const int row = wc + nt * 16 + lrow;
            bfv[nt] = *(const short8*)((const short*)Bs + row * DIM + ((g ^ (row & 15)) * 8));
        }
#pragma unroll
        for (int mt = 0; mt < 4; ++mt)
#pragma unroll
            for (int nt = 0; nt < 4; ++nt)
                acc[mt][nt] = __builtin_amdgcn_mfma_f32_16x16x32_bf16(
                    af[mt], bfv[nt], acc[mt][nt], 0, 0, 0);
    }

    // ---- epilogue: -sqrt(max(0, sq_r + sq_c - 2*gram)) ----
    // nt innermost: each thread fills 4 rows x 256 B contiguously -> L2 merge.
    const size_t orow0    = (size_t)brow * BM;
    const int    col_base = bcol * BM;
    float scb[4];
#pragma unroll
    for (int nt = 0; nt < 4; ++nt) scb[nt] = sqB[wc + nt * 16 + lrow];
#pragma unroll
    for (int mt = 0; mt < 4; ++mt) {
#pragma unroll
        for (int reg = 0; reg < 4; ++reg) {
            const int m  = wr + mt * 16 + quad * 4 + reg;  // C/D: row=(lane>>4)*4+reg, col=lane&15
            const float sr = sqA[m];
            float* orow = out + (orow0 + m) * (size_t)N_PTS + col_base;
#pragma unroll
            for (int nt = 0; nt < 4; ++nt) {
                const int n = wc + nt * 16 + lrow;
                float d2 = sr + scb[nt] - 2.0f * acc[mt][nt][reg];
                d2 = d2 > 0.f ? d2 : 0.f;
                orow[n] = -__builtin_sqrtf(d2);
            }
        }
    }
}

extern "C" void kernel_launch(void* const* d_in, const int* in_sizes, int n_in,
                              void* d_out, int out_size, void* d_ws, size_t ws_size,
                              hipStream_t stream) {
    const float* F = (const float*)d_in[0];
    float* out = (float*)d_out;
    unsigned short* bfF = (unsigned short*)d_ws;                       // 2 MB bf16
    float* sqg = (float*)((char*)d_ws + (size_t)N_PTS * DIM * 2);      // +32 KB sq

    prep_kernel<<<dim3(512), 256, 0, stream>>>(F, bfF, sqg);
    dim3 grid(N_PTS / BM, N_PTS / BM);        // 64 x 64
    fsim_kernel<<<grid, 256, 0, stream>>>(bfF, sqg, out);
}